// Round 6
// baseline (13629.480 us; speedup 1.0000x reference)
//
#include <hip/hip_runtime.h>
#include <hip/hip_bf16.h>

// GraphSAGE fused gather + weighted-mean + Linear(256->128) + ReLU
// N=100000, K=16, D=128, V=1e6 rows (f32 table).
//
// Round 6: range-phased gathers for L3 locality. Round-5 counters showed the
// kernel is fetch-path bound (~700 MB FETCH at ~4.2 TB/s random-row rate);
// ~280 MB of that is L3 capacity-miss re-fetch (512 MB table > 256 MB L3).
// Fix: iterate the gather set 4 times, phase p touching only rows with
// idx in [p*250k,(p+1)*250k). Per-phase working set ~105 MB; even with one
// phase of inter-block drift the live set fits L3, so duplicate rows hit L3
// instead of HBM. acc/wsum persist in registers across phases (statically
// indexed); self rows pack to LDS in their matching phase (exec-masked).
// Phase 2 (bf16 MFMA vs W1T) and full-row epilogue unchanged from round 5.

#define NN 100000
#define KK 16
#define DD 128
#define MM 16          // nodes per wave
#define WPB 4          // waves per block
#define NPHASE 4
#define PHSZ 250000u   // V / NPHASE

typedef __attribute__((ext_vector_type(8))) short short8;   // 8 x bf16
typedef __attribute__((ext_vector_type(4))) float f32x4;

// ---- prep: W1T[d][k] = bf16(W1[k][d]) ----
__global__ __launch_bounds__(256)
void prep_w1t_kernel(const float* __restrict__ W1, __hip_bfloat16* __restrict__ W1T)
{
    const int tid = blockIdx.x * blockDim.x + threadIdx.x;  // 32768 threads
    const int d = tid >> 8;      // 0..127
    const int k = tid & 255;     // 0..255
    W1T[d * 256 + k] = __float2bfloat16(W1[k * DD + d]);
}

static __device__ __forceinline__ unsigned pk_bf16(float a, float b) {
    __hip_bfloat162 t;
    t.x = __float2bfloat16(a);
    t.y = __float2bfloat16(b);
    return *reinterpret_cast<unsigned*>(&t);
}

__global__ __launch_bounds__(256, 4)
void graphsage_kernel(const int* __restrict__ video_nodes,
                      const int* __restrict__ neighbors,
                      const float* __restrict__ neigh_weights,
                      const float* __restrict__ emb,
                      const __hip_bfloat16* __restrict__ W1T,
                      const float* __restrict__ b1,
                      float* __restrict__ out)
{
    // per-wave slot: phase 1/2: [MM nodes][256 k] bf16 = 8 KB;
    // epilogue reuses it as [MM nodes][128 d] f32.
    __shared__ __hip_bfloat16 comb[WPB][MM][2 * DD];

    const int lane = threadIdx.x & 63;
    const int wib  = __builtin_amdgcn_readfirstlane(threadIdx.x >> 6);
    const int node0 = (blockIdx.x * WPB + wib) * MM;
    if (node0 >= NN) return;   // whole-wave exit; no barriers anywhere

    char* const slot = (char*)&comb[wib][0][0];
    const char* const embB = (const char*)emb;
    char* const outB = (char*)out;

    const int half = lane >> 5;               // which node of the pair
    const int c    = lane & 31;               // column group: floats 4c..4c+3
    const unsigned byte_c = 16u * (unsigned)c;

    // persistent across phases (statically indexed everywhere)
    f32x4 acc[MM / 2];
    float wsum[MM / 2];
    #pragma unroll
    for (int mp = 0; mp < MM / 2; ++mp) {
        acc[mp] = (f32x4){0.0f, 0.0f, 0.0f, 0.0f};
        wsum[mp] = 0.0f;
    }

    // ---- Phase 1: 4 range-phases over the gather set ----
    #pragma unroll 1
    for (int p = 0; p < NPHASE; ++p) {
        const unsigned lo = (unsigned)p * PHSZ;

        #pragma unroll
        for (int mp = 0; mp < MM / 2; ++mp) {
            const int n0 = node0 + 2 * mp;        // wave-uniform
            const int n1 = n0 + 1;

            // self row: gather+pack in its matching phase (exec-masked)
            const int s0i = video_nodes[n0];      // scalar
            const int s1i = video_nodes[n1];      // scalar
            const int sidx = half ? s1i : s0i;
            if ((unsigned)sidx - lo < PHSZ) {
                const float4 sv = *reinterpret_cast<const float4*>(
                    embB + ((((unsigned)sidx) << 9) + byte_c));
                const int nodel = 2 * mp + half;
                const unsigned swz = (unsigned)((nodel & 7) << 4);
                const unsigned sb =
                    ((unsigned)(nodel * 512) + 8u * c) ^ swz;
                uint2 sU;
                sU.x = pk_bf16(sv.x, sv.y);
                sU.y = pk_bf16(sv.z, sv.w);
                *reinterpret_cast<uint2*>(slot + sb) = sU;
            }

            #pragma unroll
            for (int k = 0; k < KK; ++k) {
                const int   i0 = neighbors[n0 * KK + k];        // scalar
                const int   i1 = neighbors[n1 * KK + k];        // scalar
                const float w0 = neigh_weights[n0 * KK + k];    // scalar
                const float w1 = neigh_weights[n1 * KK + k];    // scalar
                const int   rk = half ? i1 : i0;                // cndmask
                const float wk = half ? w1 : w0;                // cndmask
                if (p == 0) wsum[mp] += wk;                     // uniform branch
                if ((unsigned)rk - lo < PHSZ) {                 // exec-masked
                    const float4 e = *reinterpret_cast<const float4*>(
                        embB + ((((unsigned)rk) << 9) + byte_c));
                    acc[mp][0] = fmaf(wk, e.x, acc[mp][0]);
                    acc[mp][1] = fmaf(wk, e.y, acc[mp][1]);
                    acc[mp][2] = fmaf(wk, e.z, acc[mp][2]);
                    acc[mp][3] = fmaf(wk, e.w, acc[mp][3]);
                }
            }
        }
    }

    // ---- normalize + pack neighbor halves into LDS ----
    #pragma unroll
    for (int mp = 0; mp < MM / 2; ++mp) {
        const float inv = 1.0f / wsum[mp];
        const int nodel = 2 * mp + half;
        const unsigned swz = (unsigned)((nodel & 7) << 4);
        const unsigned nb = ((unsigned)(nodel * 512 + 256) + 8u * c) ^ swz;
        uint2 nU;
        nU.x = pk_bf16(acc[mp][0] * inv, acc[mp][1] * inv);
        nU.y = pk_bf16(acc[mp][2] * inv, acc[mp][3] * inv);
        *reinterpret_cast<uint2*>(slot + nb) = nU;
    }
    // wave-private slot: same-wave ds ordering via lgkmcnt + data deps.

    // ---- Phase 2: MFMA.  D[d][node] = sum_k W1T[d][k] * comb[node][k] ----
    const int nodeB  = lane & 15;    // B col / D col / output node
    const int kchunk = lane >> 4;    // 0..3
    const unsigned swzB = (unsigned)((nodeB & 7) << 4);

    short8 bfrag[8];
    #pragma unroll
    for (int kt = 0; kt < 8; ++kt) {
        const unsigned byte =
            ((unsigned)(nodeB * 512 + kt * 64 + kchunk * 16)) ^ swzB;
        bfrag[kt] = *reinterpret_cast<const short8*>(slot + byte);
    }

    const int drow = lane & 15;      // A row within d-tile
    #pragma unroll
    for (int dt = 0; dt < 8; ++dt) {
        const int d = dt * 16 + drow;
        f32x4 a = {0.0f, 0.0f, 0.0f, 0.0f};
        #pragma unroll
        for (int kt = 0; kt < 8; ++kt) {
            const short8 afrag = *reinterpret_cast<const short8*>(
                &W1T[d * 256 + kt * 32 + kchunk * 8]);
            a = __builtin_amdgcn_mfma_f32_16x16x32_bf16(afrag, bfrag[kt], a,
                                                        0, 0, 0);
        }
        // stage bias+ReLU result in the slot (f32, [node][128d], swizzled);
        // a depends on all bfrag reads -> ds_writes ordered after ds_reads.
        const int d0 = dt * 16 + kchunk * 4;
        const float4 bias = *reinterpret_cast<const float4*>(&b1[d0]);
        f32x4 r;
        r[0] = fmaxf(a[0] + bias.x, 0.0f);
        r[1] = fmaxf(a[1] + bias.y, 0.0f);
        r[2] = fmaxf(a[2] + bias.z, 0.0f);
        r[3] = fmaxf(a[3] + bias.w, 0.0f);
        const unsigned tb = ((unsigned)(nodeB * 512 + d0 * 4)) ^ swzB;
        *reinterpret_cast<f32x4*>(slot + tb) = r;
    }

    // ---- Epilogue: linear LDS read -> full-row contiguous global stores ----
    #pragma unroll
    for (int i = 0; i < 8; ++i) {
        const unsigned o     = (unsigned)i * 1024u + (unsigned)lane * 16u;
        const unsigned nodel = o >> 9;
        const unsigned rb    = o & 511u;
        const unsigned lb    = nodel * 512u + (rb ^ ((nodel & 7u) << 4));
        const float4 v = *reinterpret_cast<const float4*>(slot + lb);
        *reinterpret_cast<float4*>(
            outB + ((size_t)(node0 + nodel) << 9) + rb) = v;
    }
}

extern "C" void kernel_launch(void* const* d_in, const int* in_sizes, int n_in,
                              void* d_out, int out_size, void* d_ws, size_t ws_size,
                              hipStream_t stream) {
    const int*   video_nodes   = (const int*)d_in[0];
    const int*   neighbors     = (const int*)d_in[1];
    const float* neigh_weights = (const float*)d_in[2];
    const float* emb           = (const float*)d_in[3];
    const float* W1            = (const float*)d_in[4];
    const float* b1            = (const float*)d_in[5];
    float*       out           = (float*)d_out;

    __hip_bfloat16* W1T = (__hip_bfloat16*)d_ws;   // 64 KB

    prep_w1t_kernel<<<DD * 256 / 256, 256, 0, stream>>>(W1, W1T);

    const int nodes_per_block = WPB * MM;                          // 64
    const int grid = (NN + nodes_per_block - 1) / nodes_per_block; // 1563
    graphsage_kernel<<<grid, 256, 0, stream>>>(
        video_nodes, neighbors, neigh_weights, emb, W1T, b1, out);
}

// Round 7
// 3199.479 us; speedup vs baseline: 4.2599x; 4.2599x over previous
//
#include <hip/hip_runtime.h>
#include <hip/hip_bf16.h>

// GraphSAGE fused gather + weighted-mean + Linear(256->128) + ReLU
// N=100000, K=16, D=128, V=1e6 rows (f32 table).
//
// Round 7: range-phased gathers, spill-proof + MLP-preserving.
// Round 6 failed from (a) acc arrays -> scratch (34 GB write traffic) and
// (b) exec-masked loads serializing per-item. This version:
//   - straight-line select: out-of-phase items load row 0 (L1-hot, no HBM)
//     with weight forced to 0; no divergent branches, loads stay batched.
//   - 8 NAMED f32x4 accumulators via macro (no arrays -> no stack alloc);
//     wsum recomputed at pack time from L1-hot weights.
//   - self rows unphased (6% of traffic), phases enforce L3 reuse for the
//     16/17 neighbor traffic: all duplicates of a row share its phase.
// Phase 2 (bf16 MFMA vs W1T) + full-row epilogue unchanged from round 5.

#define NN 100000
#define KK 16
#define DD 128
#define MM 16          // nodes per wave
#define WPB 4          // waves per block
#define NPHASE 4
#define PHSZ 250000u   // V / NPHASE

typedef __attribute__((ext_vector_type(8))) short short8;   // 8 x bf16
typedef __attribute__((ext_vector_type(4))) float f32x4;

// ---- prep: W1T[d][k] = bf16(W1[k][d]) ----
__global__ __launch_bounds__(256)
void prep_w1t_kernel(const float* __restrict__ W1, __hip_bfloat16* __restrict__ W1T)
{
    const int tid = blockIdx.x * blockDim.x + threadIdx.x;  // 32768 threads
    const int d = tid >> 8;      // 0..127
    const int k = tid & 255;     // 0..255
    W1T[d * 256 + k] = __float2bfloat16(W1[k * DD + d]);
}

static __device__ __forceinline__ unsigned pk_bf16(float a, float b) {
    __hip_bfloat162 t;
    t.x = __float2bfloat16(a);
    t.y = __float2bfloat16(b);
    return *reinterpret_cast<unsigned*>(&t);
}

__global__ __launch_bounds__(256, 4)
void graphsage_kernel(const int* __restrict__ video_nodes,
                      const int* __restrict__ neighbors,
                      const float* __restrict__ neigh_weights,
                      const float* __restrict__ emb,
                      const __hip_bfloat16* __restrict__ W1T,
                      const float* __restrict__ b1,
                      float* __restrict__ out)
{
    __shared__ __hip_bfloat16 comb[WPB][MM][2 * DD];

    const int lane = threadIdx.x & 63;
    const int wib  = __builtin_amdgcn_readfirstlane(threadIdx.x >> 6);
    const int node0 = (blockIdx.x * WPB + wib) * MM;
    if (node0 >= NN) return;   // whole-wave exit; no barriers anywhere

    char* const slot = (char*)&comb[wib][0][0];
    const char* const embB = (const char*)emb;
    char* const outB = (char*)out;

    const int half = lane >> 5;               // which node of the pair
    const int c    = lane & 31;               // column group: floats 4c..4c+3
    const unsigned byte_c = 16u * (unsigned)c;

    // ---- self rows: unphased gather + pack (as round 5) ----
    #pragma unroll
    for (int mp = 0; mp < MM / 2; ++mp) {
        const int n0 = node0 + 2 * mp;
        const int s0i = video_nodes[n0];
        const int s1i = video_nodes[n0 + 1];
        const int sidx = half ? s1i : s0i;
        const float4 sv = *reinterpret_cast<const float4*>(
            embB + ((((unsigned)sidx) << 9) + byte_c));
        const int nodel = 2 * mp + half;
        const unsigned swz = (unsigned)((nodel & 7) << 4);
        const unsigned sb = ((unsigned)(nodel * 512) + 8u * c) ^ swz;
        uint2 sU;
        sU.x = pk_bf16(sv.x, sv.y);
        sU.y = pk_bf16(sv.z, sv.w);
        *reinterpret_cast<uint2*>(slot + sb) = sU;
    }

    // ---- neighbor accumulation: 4 index-range phases, named accumulators.
    // Out-of-phase items read row 0 (L1-hot) with weight 0: straight-line
    // code, loads stay batched, nothing spills.
    f32x4 a0 = {0,0,0,0}, a1 = {0,0,0,0}, a2 = {0,0,0,0}, a3 = {0,0,0,0};
    f32x4 a4 = {0,0,0,0}, a5 = {0,0,0,0}, a6 = {0,0,0,0}, a7 = {0,0,0,0};

#define PAIR_PHASE(M, AM)                                                    \
    do {                                                                     \
        const int n0 = node0 + 2 * (M);                                      \
        _Pragma("unroll")                                                    \
        for (int k = 0; k < KK; ++k) {                                       \
            const int   i0 = neighbors[n0 * KK + k];                         \
            const int   i1 = neighbors[(n0 + 1) * KK + k];                   \
            const float w0 = neigh_weights[n0 * KK + k];                     \
            const float w1 = neigh_weights[(n0 + 1) * KK + k];               \
            const int   rk = half ? i1 : i0;                                 \
            const float wk = half ? w1 : w0;                                 \
            const bool  inp = ((unsigned)rk - lo) < PHSZ;                    \
            const unsigned vo = inp ? ((((unsigned)rk) << 9) + byte_c)       \
                                    : byte_c;                                \
            const float wsel = inp ? wk : 0.0f;                              \
            const float4 e = *reinterpret_cast<const float4*>(embB + vo);    \
            AM[0] = fmaf(wsel, e.x, AM[0]);                                  \
            AM[1] = fmaf(wsel, e.y, AM[1]);                                  \
            AM[2] = fmaf(wsel, e.z, AM[2]);                                  \
            AM[3] = fmaf(wsel, e.w, AM[3]);                                  \
        }                                                                    \
    } while (0)

    #pragma unroll 1
    for (int p = 0; p < NPHASE; ++p) {
        const unsigned lo = (unsigned)p * PHSZ;
        PAIR_PHASE(0, a0);
        PAIR_PHASE(1, a1);
        PAIR_PHASE(2, a2);
        PAIR_PHASE(3, a3);
        PAIR_PHASE(4, a4);
        PAIR_PHASE(5, a5);
        PAIR_PHASE(6, a6);
        PAIR_PHASE(7, a7);
    }
#undef PAIR_PHASE

    // ---- normalize + pack neighbor halves (wsum recomputed, L1-hot) ----
#define PACK_PAIR(M, AM)                                                     \
    do {                                                                     \
        const int n0 = node0 + 2 * (M);                                      \
        float s0 = 0.0f, s1 = 0.0f;                                          \
        _Pragma("unroll")                                                    \
        for (int k = 0; k < KK; ++k) {                                       \
            s0 += neigh_weights[n0 * KK + k];                                \
            s1 += neigh_weights[(n0 + 1) * KK + k];                          \
        }                                                                    \
        const float inv = 1.0f / (half ? s1 : s0);                           \
        const int nodel = 2 * (M) + half;                                    \
        const unsigned swz = (unsigned)((nodel & 7) << 4);                   \
        const unsigned nb = ((unsigned)(nodel * 512 + 256) + 8u * c) ^ swz;  \
        uint2 nU;                                                            \
        nU.x = pk_bf16(AM[0] * inv, AM[1] * inv);                            \
        nU.y = pk_bf16(AM[2] * inv, AM[3] * inv);                            \
        *reinterpret_cast<uint2*>(slot + nb) = nU;                           \
    } while (0)

    PACK_PAIR(0, a0);
    PACK_PAIR(1, a1);
    PACK_PAIR(2, a2);
    PACK_PAIR(3, a3);
    PACK_PAIR(4, a4);
    PACK_PAIR(5, a5);
    PACK_PAIR(6, a6);
    PACK_PAIR(7, a7);
#undef PACK_PAIR
    // wave-private slot: same-wave ds ordering via lgkmcnt + data deps.

    // ---- Phase 2: MFMA.  D[d][node] = sum_k W1T[d][k] * comb[node][k] ----
    const int nodeB  = lane & 15;    // B col / D col / output node
    const int kchunk = lane >> 4;    // 0..3
    const unsigned swzB = (unsigned)((nodeB & 7) << 4);

    short8 bfrag[8];
    #pragma unroll
    for (int kt = 0; kt < 8; ++kt) {
        const unsigned byte =
            ((unsigned)(nodeB * 512 + kt * 64 + kchunk * 16)) ^ swzB;
        bfrag[kt] = *reinterpret_cast<const short8*>(slot + byte);
    }

    const int drow = lane & 15;      // A row within d-tile
    #pragma unroll
    for (int dt = 0; dt < 8; ++dt) {
        const int d = dt * 16 + drow;
        f32x4 a = {0.0f, 0.0f, 0.0f, 0.0f};
        #pragma unroll
        for (int kt = 0; kt < 8; ++kt) {
            const short8 afrag = *reinterpret_cast<const short8*>(
                &W1T[d * 256 + kt * 32 + kchunk * 8]);
            a = __builtin_amdgcn_mfma_f32_16x16x32_bf16(afrag, bfrag[kt], a,
                                                        0, 0, 0);
        }
        const int d0 = dt * 16 + kchunk * 4;
        const float4 bias = *reinterpret_cast<const float4*>(&b1[d0]);
        f32x4 r;
        r[0] = fmaxf(a[0] + bias.x, 0.0f);
        r[1] = fmaxf(a[1] + bias.y, 0.0f);
        r[2] = fmaxf(a[2] + bias.z, 0.0f);
        r[3] = fmaxf(a[3] + bias.w, 0.0f);
        const unsigned tb = ((unsigned)(nodeB * 512 + d0 * 4)) ^ swzB;
        *reinterpret_cast<f32x4*>(slot + tb) = r;
    }

    // ---- Epilogue: linear LDS read -> full-row contiguous global stores ----
    #pragma unroll
    for (int i = 0; i < 8; ++i) {
        const unsigned o     = (unsigned)i * 1024u + (unsigned)lane * 16u;
        const unsigned nodel = o >> 9;
        const unsigned rb    = o & 511u;
        const unsigned lb    = nodel * 512u + (rb ^ ((nodel & 7u) << 4));
        const float4 v = *reinterpret_cast<const float4*>(slot + lb);
        *reinterpret_cast<float4*>(
            outB + ((size_t)(node0 + nodel) << 9) + rb) = v;
    }
}

extern "C" void kernel_launch(void* const* d_in, const int* in_sizes, int n_in,
                              void* d_out, int out_size, void* d_ws, size_t ws_size,
                              hipStream_t stream) {
    const int*   video_nodes   = (const int*)d_in[0];
    const int*   neighbors     = (const int*)d_in[1];
    const float* neigh_weights = (const float*)d_in[2];
    const float* emb           = (const float*)d_in[3];
    const float* W1            = (const float*)d_in[4];
    const float* b1            = (const float*)d_in[5];
    float*       out           = (float*)d_out;

    __hip_bfloat16* W1T = (__hip_bfloat16*)d_ws;   // 64 KB

    prep_w1t_kernel<<<DD * 256 / 256, 256, 0, stream>>>(W1, W1T);

    const int nodes_per_block = WPB * MM;                          // 64
    const int grid = (NN + nodes_per_block - 1) / nodes_per_block; // 1563
    graphsage_kernel<<<grid, 256, 0, stream>>>(
        video_nodes, neighbors, neigh_weights, emb, W1T, b1, out);
}

// Round 8
// 262.409 us; speedup vs baseline: 51.9399x; 12.1927x over previous
//
#include <hip/hip_runtime.h>
#include <hip/hip_bf16.h>

// GraphSAGE fused gather + weighted-mean + Linear(256->128) + ReLU
// N=100000, K=16, D=128, V=1e6 rows (f32 table).
//
// Round 8: phase-partitioned gathers with LDS-resident partial sums.
//  - prep_sort: per node, partition 16 (idx, w/wsum) pairs into 5 index-range
//    phases (PHSZ=200k), pad to chunks of 4 with (idx=0,w=0), write
//    sorted[n][32] uint2 + nibble meta (chunk counts). ~26 MB ws.
//  - main: per (phase,node): ds_read f32x2 partial from the comb slot,
//    ~1.2 chunks x 4 batched float2 row loads (wave-uniform items via
//    s_load), ds_write back. NO persistent VGPR state across phases ->
//    cannot spill (round 6/7 failure mode). Phase working set ~82 MB,
//    <=2 phases live < 256 MB L3 -> duplicate rows hit L3 not HBM.
//  - pack self+neigh bf16, MFMA vs W1T, full-row epilogue = round 5 code.

#define NN 100000
#define KK 16
#define DD 128
#define MM 16          // nodes per wave
#define WPB 4          // waves per block
#define NPHASE 5
#define PH1 200000
#define CAP 32         // padded sorted slots per node

typedef __attribute__((ext_vector_type(8))) short short8;   // 8 x bf16
typedef __attribute__((ext_vector_type(4))) float f32x4;

// ---- prep 1: W1T[d][k] = bf16(W1[k][d]) ----
__global__ __launch_bounds__(256)
void prep_w1t_kernel(const float* __restrict__ W1, __hip_bfloat16* __restrict__ W1T)
{
    const int tid = blockIdx.x * blockDim.x + threadIdx.x;  // 32768 threads
    const int d = tid >> 8;
    const int k = tid & 255;
    W1T[d * 256 + k] = __float2bfloat16(W1[k * DD + d]);
}

// ---- prep 2: per node, phase-partition neighbors, prenormalize weights ----
__global__ __launch_bounds__(256)
void prep_sort_kernel(const int* __restrict__ neighbors,
                      const float* __restrict__ neigh_weights,
                      uint2* __restrict__ sorted,
                      unsigned* __restrict__ meta)
{
    const int n = blockIdx.x * 256 + threadIdx.x;
    if (n >= NN) return;

    int idx[KK]; float wt[KK];
    const int4*   ip = reinterpret_cast<const int4*>(neighbors + n * KK);
    const float4* wp = reinterpret_cast<const float4*>(neigh_weights + n * KK);
    #pragma unroll
    for (int q = 0; q < 4; ++q) {
        const int4   iv = ip[q];
        const float4 wv = wp[q];
        idx[4*q+0] = iv.x; idx[4*q+1] = iv.y; idx[4*q+2] = iv.z; idx[4*q+3] = iv.w;
        wt[4*q+0]  = wv.x; wt[4*q+1]  = wv.y; wt[4*q+2]  = wv.z; wt[4*q+3]  = wv.w;
    }
    float wsum = 0.0f;
    #pragma unroll
    for (int k = 0; k < KK; ++k) wsum += wt[k];
    const float inv = 1.0f / wsum;

    int ph[KK];
    int c0=0,c1=0,c2=0,c3=0,c4=0;
    #pragma unroll
    for (int k = 0; k < KK; ++k) {
        const int p = (idx[k] >= PH1) + (idx[k] >= 2*PH1) +
                      (idx[k] >= 3*PH1) + (idx[k] >= 4*PH1);
        ph[k] = p;
        c0 += (p==0); c1 += (p==1); c2 += (p==2); c3 += (p==3); c4 += (p==4);
    }
    const int h0=(c0+3)>>2, h1=(c1+3)>>2, h2=(c2+3)>>2, h3=(c3+3)>>2, h4=(c4+3)>>2;
    meta[n] = (unsigned)(h0 | (h1<<4) | (h2<<8) | (h3<<12) | (h4<<16));

    const int s1 = 4*h0, s2 = s1 + 4*h1, s3 = s2 + 4*h2, s4 = s3 + 4*h3;
    int u0 = 0, u1 = s1, u2 = s2, u3 = s3, u4 = s4;
    uint2* const base = sorted + (size_t)n * CAP;
    #pragma unroll
    for (int k = 0; k < KK; ++k) {
        const int p = ph[k];
        int pos = u0;
        pos = (p == 1) ? u1 : pos;
        pos = (p == 2) ? u2 : pos;
        pos = (p == 3) ? u3 : pos;
        pos = (p == 4) ? u4 : pos;
        uint2 item;
        item.x = (unsigned)idx[k];
        item.y = __float_as_uint(wt[k] * inv);
        base[pos] = item;
        u0 += (p==0); u1 += (p==1); u2 += (p==2); u3 += (p==3); u4 += (p==4);
    }
    // pads (<=3 per phase): idx 0, weight 0 -> exact no-op, L3-hot row
    const uint2 z = {0u, 0u};
    const int e0 = s1, e1 = s2, e2 = s3, e3 = s4, e4 = s4 + 4*h4;
    #pragma unroll
    for (int j = 0; j < 3; ++j) {
        if (u0 + j < e0) base[u0 + j] = z;
        if (u1 + j < e1) base[u1 + j] = z;
        if (u2 + j < e2) base[u2 + j] = z;
        if (u3 + j < e3) base[u3 + j] = z;
        if (u4 + j < e4) base[u4 + j] = z;
    }
}

static __device__ __forceinline__ unsigned pk_bf16(float a, float b) {
    __hip_bfloat162 t;
    t.x = __float2bfloat16(a);
    t.y = __float2bfloat16(b);
    return *reinterpret_cast<unsigned*>(&t);
}

__global__ __launch_bounds__(256, 4)
void graphsage_kernel(const int* __restrict__ video_nodes,
                      const uint2* __restrict__ sorted,
                      const unsigned* __restrict__ meta,
                      const float* __restrict__ emb,
                      const __hip_bfloat16* __restrict__ W1T,
                      const float* __restrict__ b1,
                      float* __restrict__ out)
{
    // per-wave slot, three lifetimes:
    //  (a) phase loop: f32 partial sums [16 nodes][128 f32] (lane: 8B at 8*lane)
    //  (b) comb bf16 [16 nodes][256 k], XOR-swizzled
    //  (c) epilogue f32 out [16 nodes][128 d], XOR-swizzled
    __shared__ __hip_bfloat16 comb[WPB][MM][2 * DD];

    const int lane = threadIdx.x & 63;
    const int wib  = __builtin_amdgcn_readfirstlane(threadIdx.x >> 6);
    const int node0 = (blockIdx.x * WPB + wib) * MM;
    if (node0 >= NN) return;   // whole-wave exit; no barriers anywhere

    char* const slot = (char*)&comb[wib][0][0];
    const char* const embB = (const char*)emb;
    char* const outB = (char*)out;

    const unsigned accoff = 8u * (unsigned)lane;   // both LDS acc & row voffset

    // zero the acc region
    #pragma unroll
    for (int m = 0; m < MM; ++m)
        *reinterpret_cast<float2*>(slot + m * 512 + accoff) = make_float2(0.f, 0.f);

    // per-node meta (wave-uniform scalar loads) + running chunk base
    unsigned meta_m[MM];
    unsigned base_m[MM];
    #pragma unroll
    for (int m = 0; m < MM; ++m) {
        meta_m[m] = meta[node0 + m];
        base_m[m] = 0u;
    }

    // ---- Phase 1: 5 index-range phases; partials live in LDS ----
    #pragma unroll 1
    for (int p = 0; p < NPHASE; ++p) {
        #pragma unroll
        for (int m = 0; m < MM; ++m) {
            const unsigned nch = (meta_m[m] >> (4 * p)) & 15u;
            const uint2* sp = sorted + (size_t)(node0 + m) * CAP + base_m[m];
            float2 acc =
                *reinterpret_cast<const float2*>(slot + m * 512 + accoff);
            for (unsigned ch = 0; ch < nch; ++ch) {
                const uint2 t0 = sp[ch * 4 + 0];     // wave-uniform -> s_load
                const uint2 t1 = sp[ch * 4 + 1];
                const uint2 t2 = sp[ch * 4 + 2];
                const uint2 t3 = sp[ch * 4 + 3];
                const float2 e0 = *reinterpret_cast<const float2*>(
                    embB + ((t0.x << 9) + accoff));
                const float2 e1 = *reinterpret_cast<const float2*>(
                    embB + ((t1.x << 9) + accoff));
                const float2 e2 = *reinterpret_cast<const float2*>(
                    embB + ((t2.x << 9) + accoff));
                const float2 e3 = *reinterpret_cast<const float2*>(
                    embB + ((t3.x << 9) + accoff));
                const float w0 = __uint_as_float(t0.y);
                const float w1 = __uint_as_float(t1.y);
                const float w2 = __uint_as_float(t2.y);
                const float w3 = __uint_as_float(t3.y);
                acc.x = fmaf(w0, e0.x, acc.x); acc.y = fmaf(w0, e0.y, acc.y);
                acc.x = fmaf(w1, e1.x, acc.x); acc.y = fmaf(w1, e1.y, acc.y);
                acc.x = fmaf(w2, e2.x, acc.x); acc.y = fmaf(w2, e2.y, acc.y);
                acc.x = fmaf(w3, e3.x, acc.x); acc.y = fmaf(w3, e3.y, acc.y);
            }
            *reinterpret_cast<float2*>(slot + m * 512 + accoff) = acc;
            base_m[m] += 4u * nch;
        }
    }

    // ---- pack: self gather (paired float4) + neigh partials -> comb bf16 ----
    const int half = lane >> 5;
    const int c    = lane & 31;
    const unsigned byte_c = 16u * (unsigned)c;

    float4 sv[MM / 2];
    #pragma unroll
    for (int mp = 0; mp < MM / 2; ++mp) {
        const int n0 = node0 + 2 * mp;
        const int s0i = video_nodes[n0];
        const int s1i = video_nodes[n0 + 1];
        const int sidx = half ? s1i : s0i;
        sv[mp] = *reinterpret_cast<const float4*>(
            embB + ((((unsigned)sidx) << 9) + byte_c));
    }

    #pragma unroll
    for (int mp = 0; mp < MM / 2; ++mp) {
        const int m0 = 2 * mp, m1 = 2 * mp + 1;
        // read partials of BOTH rows before any write touches them
        const float2 A0 =
            *reinterpret_cast<const float2*>(slot + m0 * 512 + accoff);
        const float2 A1 =
            *reinterpret_cast<const float2*>(slot + m1 * 512 + accoff);
        // neigh bf16: element 128+d at byte (m*512+256+2d)^swz; lane owns d=2l,2l+1
        const unsigned sz0 = (unsigned)((m0 & 7) << 4);
        const unsigned sz1 = (unsigned)((m1 & 7) << 4);
        const unsigned nb0 =
            ((unsigned)(m0 * 512 + 256) + 4u * (unsigned)lane) ^ sz0;
        const unsigned nb1 =
            ((unsigned)(m1 * 512 + 256) + 4u * (unsigned)lane) ^ sz1;
        *reinterpret_cast<unsigned*>(slot + nb0) = pk_bf16(A0.x, A0.y);
        *reinterpret_cast<unsigned*>(slot + nb1) = pk_bf16(A1.x, A1.y);
        // self bf16 (paired layout, as round 5)
        const int nodel = 2 * mp + half;
        const unsigned swz = (unsigned)((nodel & 7) << 4);
        const unsigned sb = ((unsigned)(nodel * 512) + 8u * (unsigned)c) ^ swz;
        uint2 sU;
        sU.x = pk_bf16(sv[mp].x, sv[mp].y);
        sU.y = pk_bf16(sv[mp].z, sv[mp].w);
        *reinterpret_cast<uint2*>(slot + sb) = sU;
    }
    // wave-private slot: same-wave ds ordering via lgkmcnt + data deps.

    // ---- Phase 2: MFMA.  D[d][node] = sum_k W1T[d][k] * comb[node][k] ----
    const int nodeB  = lane & 15;
    const int kchunk = lane >> 4;
    const unsigned swzB = (unsigned)((nodeB & 7) << 4);

    short8 bfrag[8];
    #pragma unroll
    for (int kt = 0; kt < 8; ++kt) {
        const unsigned byte =
            ((unsigned)(nodeB * 512 + kt * 64 + kchunk * 16)) ^ swzB;
        bfrag[kt] = *reinterpret_cast<const short8*>(slot + byte);
    }

    const int drow = lane & 15;
    #pragma unroll
    for (int dt = 0; dt < 8; ++dt) {
        const int d = dt * 16 + drow;
        f32x4 a = {0.0f, 0.0f, 0.0f, 0.0f};
        #pragma unroll
        for (int kt = 0; kt < 8; ++kt) {
            const short8 afrag = *reinterpret_cast<const short8*>(
                &W1T[d * 256 + kt * 32 + kchunk * 8]);
            a = __builtin_amdgcn_mfma_f32_16x16x32_bf16(afrag, bfrag[kt], a,
                                                        0, 0, 0);
        }
        const int d0 = dt * 16 + kchunk * 4;
        const float4 bias = *reinterpret_cast<const float4*>(&b1[d0]);
        f32x4 r;
        r[0] = fmaxf(a[0] + bias.x, 0.0f);
        r[1] = fmaxf(a[1] + bias.y, 0.0f);
        r[2] = fmaxf(a[2] + bias.z, 0.0f);
        r[3] = fmaxf(a[3] + bias.w, 0.0f);
        const unsigned tb = ((unsigned)(nodeB * 512 + d0 * 4)) ^ swzB;
        *reinterpret_cast<f32x4*>(slot + tb) = r;
    }

    // ---- Epilogue: linear LDS read -> full-row contiguous global stores ----
    #pragma unroll
    for (int i = 0; i < 8; ++i) {
        const unsigned o     = (unsigned)i * 1024u + (unsigned)lane * 16u;
        const unsigned nodel = o >> 9;
        const unsigned rb    = o & 511u;
        const unsigned lb    = nodel * 512u + (rb ^ ((nodel & 7u) << 4));
        const float4 v = *reinterpret_cast<const float4*>(slot + lb);
        *reinterpret_cast<float4*>(
            outB + ((size_t)(node0 + nodel) << 9) + rb) = v;
    }
}

extern "C" void kernel_launch(void* const* d_in, const int* in_sizes, int n_in,
                              void* d_out, int out_size, void* d_ws, size_t ws_size,
                              hipStream_t stream) {
    const int*   video_nodes   = (const int*)d_in[0];
    const int*   neighbors     = (const int*)d_in[1];
    const float* neigh_weights = (const float*)d_in[2];
    const float* emb           = (const float*)d_in[3];
    const float* W1            = (const float*)d_in[4];
    const float* b1            = (const float*)d_in[5];
    float*       out           = (float*)d_out;

    char* ws = (char*)d_ws;
    __hip_bfloat16* W1T   = (__hip_bfloat16*)ws;                   // 64 KB
    uint2*          sorted = (uint2*)(ws + 65536);                 // 25.6 MB
    unsigned*       meta   = (unsigned*)(ws + 65536 + (size_t)NN * CAP * 8); // 400 KB

    prep_w1t_kernel<<<DD * 256 / 256, 256, 0, stream>>>(W1, W1T);
    prep_sort_kernel<<<(NN + 255) / 256, 256, 0, stream>>>(
        neighbors, neigh_weights, sorted, meta);

    const int nodes_per_block = WPB * MM;                          // 64
    const int grid = (NN + nodes_per_block - 1) / nodes_per_block; // 1563
    graphsage_kernel<<<grid, 256, 0, stream>>>(
        video_nodes, sorted, meta, emb, W1T, b1, out);
}